// Round 2
// baseline (1703.734 us; speedup 1.0000x reference)
//
#include <hip/hip_runtime.h>

#define GRID 64
#define NVOX (GRID*GRID*GRID)
#define NCLS 20
#define NSEED 512

// ---------------- weight transpose: [oc][ci][dz][dy][dx] -> [(nb*ci)][oc] ----------------
__global__ void transpose_w1(const float* __restrict__ w, float* __restrict__ wt) {
    int t = blockIdx.x * 256 + threadIdx.x;      // over 27*6*64
    if (t >= 27 * 6 * 64) return;
    int oc = t & 63;
    int r  = t >> 6;            // r = nb*6 + ci
    int nb = r / 6, ci = r % 6;
    wt[t] = w[oc * 162 + ci * 27 + nb];
}

__global__ void transpose_w2(const float* __restrict__ w, float* __restrict__ wt) {
    int t = blockIdx.x * 256 + threadIdx.x;      // over 27*64*32
    if (t >= 27 * 64 * 32) return;
    int oc = t & 31;
    int r  = t >> 5;            // r = nb*64 + ci
    int nb = r >> 6, ci = r & 63;
    wt[t] = w[oc * 1728 + ci * 27 + nb];
}

// ---------------- conv1 (6->64) + relu, output channel-last h1[vox][64] ----------------
__global__ __launch_bounds__(256) void conv1_kernel(
    const float* __restrict__ feat,   // [6][64][64][64]
    const float* __restrict__ w1t,    // [(nb*6+ci)][64]
    const float* __restrict__ b1,
    float* __restrict__ h1)           // [vox][64]
{
    int bx = blockIdx.x;              // z*16 + ytile
    int z  = bx >> 4, yt = bx & 15;
    int x  = threadIdx.x & 63;
    int y  = yt * 4 + (threadIdx.x >> 6);

    float acc[64];
    #pragma unroll
    for (int o = 0; o < 64; ++o) acc[o] = b1[o];

    for (int dz = -1; dz <= 1; ++dz) {
      int nz = z + dz; bool okz = (unsigned)nz < 64u; int cz = okz ? nz : (nz < 0 ? 0 : 63);
      for (int dy = -1; dy <= 1; ++dy) {
        int ny = y + dy; bool oky = (unsigned)ny < 64u; int cy = oky ? ny : (ny < 0 ? 0 : 63);
        for (int dx = -1; dx <= 1; ++dx) {
          int nx = x + dx; bool okx = (unsigned)nx < 64u; int cx = okx ? nx : (nx < 0 ? 0 : 63);
          float m = (okz && oky && okx) ? 1.0f : 0.0f;
          int nb = (dz + 1) * 9 + (dy + 1) * 3 + (dx + 1);
          int voff = (cz * 64 + cy) * 64 + cx;
          const float* wr = w1t + nb * 6 * 64;   // wave-uniform -> s_load
          #pragma unroll
          for (int ci = 0; ci < 6; ++ci) {
            float v = feat[(size_t)ci * NVOX + voff] * m;
            const float* wc = wr + ci * 64;
            #pragma unroll
            for (int o = 0; o < 64; ++o) acc[o] = fmaf(v, wc[o], acc[o]);
          }
        }
      }
    }

    float* dst = h1 + ((size_t)((z * 64 + y) * 64 + x)) * 64;
    #pragma unroll
    for (int o = 0; o < 64; o += 4) {
        float4 v = make_float4(fmaxf(acc[o], 0.f), fmaxf(acc[o+1], 0.f),
                               fmaxf(acc[o+2], 0.f), fmaxf(acc[o+3], 0.f));
        *reinterpret_cast<float4*>(dst + o) = v;
    }
}

// ------- conv2 (64->32) via LDS halo tiles + relu + heads + argmin + scatter -------
// block = 8x8x4 voxel tile; per 8-channel chunk stage 10x10x6 zero-padded halo in LDS
__global__ __launch_bounds__(256) void conv2_fused_kernel(
    const float* __restrict__ h1,     // [vox][64]
    const float* __restrict__ w2t,    // [(nb*64+ci)][32]
    const float* __restrict__ b2,
    const float* __restrict__ points, // [N][3]
    const float* __restrict__ ann,    // [512][4]
    const float* __restrict__ sem_w, const float* __restrict__ sem_b,
    const float* __restrict__ off_w, const float* __restrict__ off_b,
    float* __restrict__ out_logits,   // [N][20]
    float* __restrict__ out_off,      // [N][3]
    int* __restrict__ iv_out,         // [N]  valid ? inst : -1
    int* __restrict__ bad_seed)       // [512]
{
    __shared__ float  sh[8 * 6 * 10 * 11];   // [ci8][z6][y10][x11(pad)] = 21120 B
    __shared__ float4 sseed[NSEED];          // 8192 B

    int tid = threadIdx.x;
    for (int i = tid; i < NSEED; i += 256) {
        float a0 = ann[i*4+0], a1 = ann[i*4+1], a2 = ann[i*4+2];
        sseed[i] = make_float4(a0, a1, a2, a0*a0 + a1*a1 + a2*a2);
    }

    int bid = blockIdx.x;                 // 8 x-tiles, 8 y-tiles, 16 z-tiles
    int bx0 = (bid & 7) * 8;
    int by0 = ((bid >> 3) & 7) * 8;
    int bz0 = (bid >> 6) * 4;

    int lx = tid & 7;
    int ly = (tid >> 3) & 7;
    int lz = tid >> 6;                    // wave-uniform (wave = one z slice)

    int x = bx0 + lx, y = by0 + ly, z = bz0 + lz;
    int vox = (z * 64 + y) * 64 + x;

    float acc[32];
    #pragma unroll
    for (int o = 0; o < 32; ++o) acc[o] = b2[o];

    for (int c = 0; c < 8; ++c) {         // 8 chunks of 8 input channels
        __syncthreads();                  // protect sh from previous chunk's readers
        // ---- stage zero-padded halo: 10x10x6 voxels x 8 channels ----
        for (int t = tid; t < 4800; t += 256) {
            int ci   = t & 7;
            int rest = t >> 3;            // 0..599
            int xx   = rest % 10;
            int r2   = rest / 10;
            int yy   = r2 % 10;
            int zz   = r2 / 10;           // 0..5
            int gx = bx0 + xx - 1, gy = by0 + yy - 1, gz = bz0 + zz - 1;
            float v = 0.f;
            if ((unsigned)gx < 64u && (unsigned)gy < 64u && (unsigned)gz < 64u)
                v = h1[((size_t)((gz * 64 + gy) * 64 + gx)) * 64 + c * 8 + ci];
            sh[((ci * 6 + zz) * 10 + yy) * 11 + xx] = v;
        }
        __syncthreads();
        // ---- accumulate 27 taps x 8 ci x 32 oc ----
        for (int dz = 0; dz < 3; ++dz)
        for (int dy = 0; dy < 3; ++dy)
        for (int dx = 0; dx < 3; ++dx) {
            int nb = (dz * 9 + dy * 3 + dx);
            const float* wr = w2t + (size_t)(nb * 64 + c * 8) * 32;  // wave-uniform
            #pragma unroll
            for (int ci = 0; ci < 8; ++ci) {
                float v = sh[((ci * 6 + lz + dz) * 10 + ly + dy) * 11 + lx + dx];
                const float* wc = wr + ci * 32;
                #pragma unroll
                for (int o = 0; o < 32; ++o) acc[o] = fmaf(v, wc[o], acc[o]);
            }
        }
    }

    // relu -> pf
    #pragma unroll
    for (int o = 0; o < 32; ++o) acc[o] = fmaxf(acc[o], 0.f);

    // semantic head + argmax (strict > matches numpy first-occurrence)
    float best = -1e30f; int am = 0;
    #pragma unroll
    for (int cc = 0; cc < NCLS; ++cc) {
        float l = sem_b[cc];
        #pragma unroll
        for (int f = 0; f < 32; ++f) l = fmaf(acc[f], sem_w[cc * 32 + f], l);
        out_logits[(size_t)vox * NCLS + cc] = l;
        if (l > best) { best = l; am = cc; }
    }

    // offset head
    float off[3];
    #pragma unroll
    for (int k = 0; k < 3; ++k) {
        float l = off_b[k];
        #pragma unroll
        for (int f = 0; f < 32; ++f) l = fmaf(acc[f], off_w[k * 32 + f], l);
        out_off[(size_t)vox * 3 + k] = l;
        off[k] = l;
    }

    float px = points[(size_t)vox * 3 + 0] + off[0];
    float py = points[(size_t)vox * 3 + 1] + off[1];
    float pz = points[(size_t)vox * 3 + 2] + off[2];
    float pp = px * px + py * py + pz * pz;

    // nearest seed (argmin on d2; sqrt monotone). strict < = first-occurrence.
    float bd2 = 1e30f; int bj = 0;
    for (int j = 0; j < NSEED; ++j) {
        float4 s = sseed[j];                    // LDS broadcast, conflict-free
        float dot = px * s.x + py * s.y + pz * s.z;
        float d2  = pp + s.w - 2.0f * dot;
        if (d2 < bd2) { bd2 = d2; bj = j; }
    }
    float mind = sqrtf(fmaxf(bd2, 0.f));
    bool valid = mind < 1.5f;

    int slab = (int)ann[bj * 4 + 3];
    if (valid && am != slab) atomicOr(&bad_seed[bj], 1);
    iv_out[vox] = valid ? bj : -1;
}

// ---------------- finalize pseudo labels ----------------
__global__ void finalize_kernel(const int* __restrict__ iv,
                                const int* __restrict__ bad,
                                float* __restrict__ pl) {
    int t = blockIdx.x * 256 + threadIdx.x;
    if (t >= NVOX) return;
    int v = iv[t];
    float r = -1.0f;
    if (v >= 0 && bad[v] == 0) r = (float)v;
    pl[t] = r;
}

extern "C" void kernel_launch(void* const* d_in, const int* in_sizes, int n_in,
                              void* d_out, int out_size, void* d_ws, size_t ws_size,
                              hipStream_t stream) {
    const float* points   = (const float*)d_in[0];
    const float* features = (const float*)d_in[1];
    const float* ann      = (const float*)d_in[2];
    const float* w1       = (const float*)d_in[3];
    const float* b1       = (const float*)d_in[4];
    const float* w2       = (const float*)d_in[5];
    const float* b2       = (const float*)d_in[6];
    const float* sem_w    = (const float*)d_in[7];
    const float* sem_b    = (const float*)d_in[8];
    const float* off_w    = (const float*)d_in[9];
    const float* off_b    = (const float*)d_in[10];

    float* out        = (float*)d_out;
    float* out_logits = out;
    float* out_off    = out + (size_t)NVOX * NCLS;   // N*20
    float* out_pl     = out + (size_t)NVOX * 23;     // N*23

    // workspace layout (bytes, 256-aligned)
    char*  ws  = (char*)d_ws;
    float* w1t = (float*)(ws);                 //   41472 B
    float* w2t = (float*)(ws + 41472);         //  221184 B
    int*   bad = (int*)  (ws + 262656);        //    2048 B
    int*   iv  = (int*)  (ws + 264704);        // 1048576 B
    float* h1  = (float*)(ws + 1313280);       // 67108864 B  (total ~65.3 MB)

    hipMemsetAsync(bad, 0, NSEED * sizeof(int), stream);
    transpose_w1<<<41, 256, 0, stream>>>(w1, w1t);
    transpose_w2<<<216, 256, 0, stream>>>(w2, w2t);
    conv1_kernel<<<1024, 256, 0, stream>>>(features, w1t, b1, h1);
    conv2_fused_kernel<<<1024, 256, 0, stream>>>(h1, w2t, b2, points, ann,
        sem_w, sem_b, off_w, off_b, out_logits, out_off, iv, bad);
    finalize_kernel<<<1024, 256, 0, stream>>>(iv, bad, out_pl);
}

// Round 3
// 710.867 us; speedup vs baseline: 2.3967x; 2.3967x over previous
//
#include <hip/hip_runtime.h>

#define GRID 64
#define NVOX (GRID*GRID*GRID)
#define NCLS 20
#define NSEED 512

// ---------------- weight transpose: [oc][ci][dz][dy][dx] -> [(nb*64+ci)][oc] ----------------
__global__ void transpose_w1(const float* __restrict__ w, float* __restrict__ wt) {
    int t = blockIdx.x * 256 + threadIdx.x;      // over 27*6*64
    if (t >= 27 * 6 * 64) return;
    int oc = t & 63;
    int r  = t >> 6;            // r = nb*6 + ci
    int nb = r / 6, ci = r % 6;
    wt[t] = w[oc * 162 + ci * 27 + nb];
}

__global__ void transpose_w2(const float* __restrict__ w, float* __restrict__ wt) {
    int t = blockIdx.x * 256 + threadIdx.x;      // over 27*64*32
    if (t >= 27 * 64 * 32) return;
    int oc = t & 31;
    int r  = t >> 5;            // r = nb*64 + ci
    int nb = r >> 6, ci = r & 63;
    wt[t] = w[oc * 1728 + ci * 27 + nb];
}

// ---------------- conv1 (6->64) + relu, output channel-last h1[vox][64] ----------------
__global__ __launch_bounds__(256) void conv1_kernel(
    const float* __restrict__ feat,   // [6][64][64][64]
    const float* __restrict__ w1t,    // [(nb*6+ci)][64]
    const float* __restrict__ b1,
    float* __restrict__ h1)           // [vox][64]
{
    int bx = blockIdx.x;              // z*16 + ytile
    int z  = bx >> 4, yt = bx & 15;
    int x  = threadIdx.x & 63;
    int y  = yt * 4 + (threadIdx.x >> 6);

    float acc[64];
    #pragma unroll
    for (int o = 0; o < 64; ++o) acc[o] = b1[o];

    for (int dz = -1; dz <= 1; ++dz) {
      int nz = z + dz; bool okz = (unsigned)nz < 64u; int cz = okz ? nz : (nz < 0 ? 0 : 63);
      for (int dy = -1; dy <= 1; ++dy) {
        int ny = y + dy; bool oky = (unsigned)ny < 64u; int cy = oky ? ny : (ny < 0 ? 0 : 63);
        if (!(okz && oky)) continue;          // wave-uniform skip (y,z uniform per wave)
        #pragma unroll
        for (int dx = -1; dx <= 1; ++dx) {
          int nx = x + dx; bool okx = (unsigned)nx < 64u; int cx = okx ? nx : (nx < 0 ? 0 : 63);
          float m = okx ? 1.0f : 0.0f;
          int nb = (dz + 1) * 9 + (dy + 1) * 3 + (dx + 1);
          int voff = (cz * 64 + cy) * 64 + cx;
          const float* wr = w1t + nb * 6 * 64;   // wave-uniform -> s_load
          #pragma unroll
          for (int ci = 0; ci < 6; ++ci) {
            float v = feat[(size_t)ci * NVOX + voff] * m;
            const float* wc = wr + ci * 64;
            #pragma unroll
            for (int o = 0; o < 64; ++o) acc[o] = fmaf(v, wc[o], acc[o]);
          }
        }
      }
    }

    float* dst = h1 + ((size_t)((z * 64 + y) * 64 + x)) * 64;
    #pragma unroll
    for (int o = 0; o < 64; o += 4) {
        float4 v = make_float4(fmaxf(acc[o], 0.f), fmaxf(acc[o+1], 0.f),
                               fmaxf(acc[o+2], 0.f), fmaxf(acc[o+3], 0.f));
        *reinterpret_cast<float4*>(dst + o) = v;
    }
}

// ------- conv2 (64->32), oc split in halves of 16; XCD-chunked z; writes pf (post-relu) -------
// grid 2048: logical L = (B&7)*256 + (B>>3); chunk c=L>>8 owns z in [c*8, c*8+8) on XCD B%8.
__global__ __launch_bounds__(256, 8) void conv2_half_kernel(
    const float* __restrict__ h1,     // [vox][64]
    const float* __restrict__ w2t,    // [(nb*64+ci)][32]
    const float* __restrict__ b2,
    float* __restrict__ pf)           // [vox][32] post-relu
{
    int B = blockIdx.x;
    int L = (B & 7) * 256 + (B >> 3);
    int c  = L >> 8;                  // z-chunk 0..7
    int r  = L & 255;
    int h  = r & 1;                   // oc half
    int zt = (r >> 1) >> 4;           // 0..7
    int yt = (r >> 1) & 15;           // 0..15
    int z  = c * 8 + zt;
    int x  = threadIdx.x & 63;
    int y  = yt * 4 + (threadIdx.x >> 6);   // wave-uniform y

    const float* bh = b2 + h * 16;
    float acc[16];
    #pragma unroll
    for (int o = 0; o < 16; ++o) acc[o] = bh[o];

    for (int dz = -1; dz <= 1; ++dz) {
      int nz = z + dz; if ((unsigned)nz >= 64u) continue;     // block-uniform
      for (int dy = -1; dy <= 1; ++dy) {
        int ny = y + dy; if ((unsigned)ny >= 64u) continue;   // wave-uniform
        #pragma unroll
        for (int dx = -1; dx <= 1; ++dx) {
          int nx = x + dx; bool okx = (unsigned)nx < 64u; int cx = okx ? nx : (nx < 0 ? 0 : 63);
          float m = okx ? 1.0f : 0.0f;
          int nb = (dz + 1) * 9 + (dy + 1) * 3 + (dx + 1);
          const float* src = h1 + ((size_t)((nz * 64 + ny) * 64 + cx)) * 64;
          const float* wr  = w2t + (size_t)nb * 64 * 32 + h * 16;   // wave-uniform
          #pragma unroll 4
          for (int c4 = 0; c4 < 16; ++c4) {
            float4 iv = *reinterpret_cast<const float4*>(src + c4 * 4);
            iv.x *= m; iv.y *= m; iv.z *= m; iv.w *= m;
            const float* wc = wr + c4 * 4 * 32;
            #pragma unroll
            for (int o = 0; o < 16; ++o) acc[o] = fmaf(iv.x, wc[o],      acc[o]);
            #pragma unroll
            for (int o = 0; o < 16; ++o) acc[o] = fmaf(iv.y, wc[32 + o], acc[o]);
            #pragma unroll
            for (int o = 0; o < 16; ++o) acc[o] = fmaf(iv.z, wc[64 + o], acc[o]);
            #pragma unroll
            for (int o = 0; o < 16; ++o) acc[o] = fmaf(iv.w, wc[96 + o], acc[o]);
          }
        }
      }
    }

    float* dst = pf + ((size_t)((z * 64 + y) * 64 + x)) * 32 + h * 16;
    #pragma unroll
    for (int o = 0; o < 16; o += 4) {
        float4 v = make_float4(fmaxf(acc[o], 0.f), fmaxf(acc[o+1], 0.f),
                               fmaxf(acc[o+2], 0.f), fmaxf(acc[o+3], 0.f));
        *reinterpret_cast<float4*>(dst + o) = v;
    }
}

// ------- epilogue: heads + argmax + argmin over seeds + mismatch scatter -------
__global__ __launch_bounds__(256) void epilogue_kernel(
    const float* __restrict__ pf,     // [vox][32] post-relu
    const float* __restrict__ points, // [N][3]
    const float* __restrict__ ann,    // [512][4]
    const float* __restrict__ sem_w, const float* __restrict__ sem_b,
    const float* __restrict__ off_w, const float* __restrict__ off_b,
    float* __restrict__ out_logits,   // [N][20]
    float* __restrict__ out_off,      // [N][3]
    int* __restrict__ iv_out,         // [N]
    int* __restrict__ bad_seed)       // [512]
{
    __shared__ float4 sseed[NSEED];
    for (int i = threadIdx.x; i < NSEED; i += 256) {
        float4 a = *reinterpret_cast<const float4*>(ann + i * 4);
        sseed[i] = make_float4(a.x, a.y, a.z, a.x*a.x + a.y*a.y + a.z*a.z);
    }
    __syncthreads();

    int vox = blockIdx.x * 256 + threadIdx.x;

    float f[32];
    #pragma unroll
    for (int q = 0; q < 8; ++q) {
        float4 v = *reinterpret_cast<const float4*>(pf + (size_t)vox * 32 + q * 4);
        f[q*4+0] = v.x; f[q*4+1] = v.y; f[q*4+2] = v.z; f[q*4+3] = v.w;
    }

    // semantic head + argmax (strict > = first occurrence)
    float best = -1e30f; int am = 0;
    #pragma unroll
    for (int cc = 0; cc < NCLS; ++cc) {
        float l = sem_b[cc];
        #pragma unroll
        for (int k = 0; k < 32; ++k) l = fmaf(f[k], sem_w[cc * 32 + k], l);
        out_logits[(size_t)vox * NCLS + cc] = l;
        if (l > best) { best = l; am = cc; }
    }

    // offset head
    float off[3];
    #pragma unroll
    for (int k3 = 0; k3 < 3; ++k3) {
        float l = off_b[k3];
        #pragma unroll
        for (int k = 0; k < 32; ++k) l = fmaf(f[k], off_w[k3 * 32 + k], l);
        out_off[(size_t)vox * 3 + k3] = l;
        off[k3] = l;
    }

    float px = points[(size_t)vox * 3 + 0] + off[0];
    float py = points[(size_t)vox * 3 + 1] + off[1];
    float pz = points[(size_t)vox * 3 + 2] + off[2];
    float pp = px * px + py * py + pz * pz;

    float bd2 = 1e30f; int bj = 0;
    #pragma unroll 4
    for (int j = 0; j < NSEED; ++j) {
        float4 s = sseed[j];                    // broadcast, conflict-free
        float dot = px * s.x + py * s.y + pz * s.z;
        float d2  = pp + s.w - 2.0f * dot;
        if (d2 < bd2) { bd2 = d2; bj = j; }
    }
    float mind = sqrtf(fmaxf(bd2, 0.f));
    bool valid = mind < 1.5f;

    int slab = (int)ann[bj * 4 + 3];
    if (valid && am != slab) atomicOr(&bad_seed[bj], 1);
    iv_out[vox] = valid ? bj : -1;
}

// ---------------- finalize pseudo labels ----------------
__global__ void finalize_kernel(const int* __restrict__ iv,
                                const int* __restrict__ bad,
                                float* __restrict__ pl) {
    int t = blockIdx.x * 256 + threadIdx.x;
    if (t >= NVOX) return;
    int v = iv[t];
    float r = -1.0f;
    if (v >= 0 && bad[v] == 0) r = (float)v;
    pl[t] = r;
}

extern "C" void kernel_launch(void* const* d_in, const int* in_sizes, int n_in,
                              void* d_out, int out_size, void* d_ws, size_t ws_size,
                              hipStream_t stream) {
    const float* points   = (const float*)d_in[0];
    const float* features = (const float*)d_in[1];
    const float* ann      = (const float*)d_in[2];
    const float* w1       = (const float*)d_in[3];
    const float* b1       = (const float*)d_in[4];
    const float* w2       = (const float*)d_in[5];
    const float* b2       = (const float*)d_in[6];
    const float* sem_w    = (const float*)d_in[7];
    const float* sem_b    = (const float*)d_in[8];
    const float* off_w    = (const float*)d_in[9];
    const float* off_b    = (const float*)d_in[10];

    float* out        = (float*)d_out;
    float* out_logits = out;
    float* out_off    = out + (size_t)NVOX * NCLS;   // N*20
    float* out_pl     = out + (size_t)NVOX * 23;     // N*23

    // workspace layout (bytes, 256-aligned)
    char*  ws  = (char*)d_ws;
    float* w1t = (float*)(ws);                 //    41472 B
    float* w2t = (float*)(ws + 41472);         //   221184 B
    int*   bad = (int*)  (ws + 262656);        //     2048 B
    int*   iv  = (int*)  (ws + 264704);        //  1048576 B
    float* pf  = (float*)(ws + 1313280);       // 33554432 B
    float* h1  = (float*)(ws + 34867712);      // 67108864 B  (total ~97.3 MB)

    hipMemsetAsync(bad, 0, NSEED * sizeof(int), stream);
    transpose_w1<<<41, 256, 0, stream>>>(w1, w1t);
    transpose_w2<<<216, 256, 0, stream>>>(w2, w2t);
    conv1_kernel<<<1024, 256, 0, stream>>>(features, w1t, b1, h1);
    conv2_half_kernel<<<2048, 256, 0, stream>>>(h1, w2t, b2, pf);
    epilogue_kernel<<<1024, 256, 0, stream>>>(pf, points, ann,
        sem_w, sem_b, off_w, off_b, out_logits, out_off, iv, bad);
    finalize_kernel<<<1024, 256, 0, stream>>>(iv, bad, out_pl);
}

// Round 4
// 666.119 us; speedup vs baseline: 2.5577x; 1.0672x over previous
//
#include <hip/hip_runtime.h>

#define GRID 64
#define NVOX (GRID*GRID*GRID)
#define NCLS 20
#define NSEED 512

// ---------------- weight transposes, one launch ----------------
// w1t[(nb*6+ci)*64+oc] = w1[oc][ci][nb];  w2t[(nb*64+ci)*32+oc] = w2[oc][ci][nb]
__global__ void transpose_all(const float* __restrict__ w1, float* __restrict__ w1t,
                              const float* __restrict__ w2, float* __restrict__ w2t) {
    int t = blockIdx.x * 256 + threadIdx.x;
    if (t < 27 * 6 * 64) {
        int oc = t & 63;
        int r  = t >> 6;            // nb*6 + ci
        int nb = r / 6, ci = r % 6;
        w1t[t] = w1[oc * 162 + ci * 27 + nb];
        return;
    }
    t -= 27 * 6 * 64;
    if (t < 27 * 64 * 32) {
        int oc = t & 31;
        int r  = t >> 5;            // nb*64 + ci
        int nb = r >> 6, ci = r & 63;
        w2t[t] = w2[oc * 1728 + ci * 27 + nb];
    }
}

// ---------------- conv1 (6->64) + relu, h1[vox][64]; XCD z-chunked dispatch ----------------
__global__ __launch_bounds__(256) void conv1_kernel(
    const float* __restrict__ feat,   // [6][64][64][64]
    const float* __restrict__ w1t,    // [(nb*6+ci)][64]
    const float* __restrict__ b1,
    float* __restrict__ h1)           // [vox][64]
{
    int B = blockIdx.x;               // 1024
    int c = B & 7, k = B >> 3;        // chunk c on XCD c (round-robin)
    int z = c * 8 + (k >> 4);
    int yt = k & 15;
    int x  = threadIdx.x & 63;
    int y  = yt * 4 + (threadIdx.x >> 6);

    float acc[64];
    #pragma unroll
    for (int o = 0; o < 64; ++o) acc[o] = b1[o];

    #pragma unroll 1
    for (int dz = -1; dz <= 1; ++dz) {
      int nz = z + dz; if ((unsigned)nz >= 64u) continue;     // block-uniform (zero pad)
      #pragma unroll 1
      for (int dy = -1; dy <= 1; ++dy) {
        int ny = y + dy; if ((unsigned)ny >= 64u) continue;   // wave-uniform
        #pragma unroll 1
        for (int dx = -1; dx <= 1; ++dx) {
          int nx = x + dx; bool okx = (unsigned)nx < 64u; int cx = okx ? nx : (nx < 0 ? 0 : 63);
          float m = okx ? 1.0f : 0.0f;
          int nb = (dz + 1) * 9 + (dy + 1) * 3 + (dx + 1);
          int voff = (nz * 64 + ny) * 64 + cx;
          const float* wr = w1t + nb * 6 * 64;   // wave-uniform -> s_load
          #pragma unroll
          for (int ci = 0; ci < 6; ++ci) {
            float v = feat[(size_t)ci * NVOX + voff] * m;
            const float* wc = wr + ci * 64;
            #pragma unroll
            for (int o = 0; o < 64; ++o) acc[o] = fmaf(v, wc[o], acc[o]);
          }
        }
      }
    }

    float* dst = h1 + ((size_t)((z * 64 + y) * 64 + x)) * 64;
    #pragma unroll
    for (int o = 0; o < 64; o += 4) {
        float4 v = make_float4(fmaxf(acc[o], 0.f), fmaxf(acc[o+1], 0.f),
                               fmaxf(acc[o+2], 0.f), fmaxf(acc[o+3], 0.f));
        *reinterpret_cast<float4*>(dst + o) = v;
    }
}

// ------- conv2 (64->32): full acc[32], full-row load batching, z-major XCD dispatch -------
__global__ __launch_bounds__(256, 4) void conv2_kernel(
    const float* __restrict__ h1,     // [vox][64]
    const float* __restrict__ w2t,    // [(nb*64+ci)][32]
    const float* __restrict__ b2,
    float* __restrict__ pf)           // [vox][32] post-relu
{
    int B = blockIdx.x;               // 1024
    int c = B & 7, k = B >> 3;        // chunk c -> XCD c; k z-major => L2 window ~4 planes
    int z = c * 8 + (k >> 4);
    int yt = k & 15;
    int x  = threadIdx.x & 63;
    int y  = yt * 4 + (threadIdx.x >> 6);   // wave-uniform y

    float acc[32];
    #pragma unroll
    for (int o = 0; o < 32; ++o) acc[o] = b2[o];

    #pragma unroll 1
    for (int dz = -1; dz <= 1; ++dz) {
      int nz = z + dz; if ((unsigned)nz >= 64u) continue;     // block-uniform (zero pad)
      #pragma unroll 1
      for (int dy = -1; dy <= 1; ++dy) {
        int ny = y + dy; if ((unsigned)ny >= 64u) continue;   // wave-uniform
        #pragma unroll 1
        for (int dx = -1; dx <= 1; ++dx) {
          int nx = x + dx; bool okx = (unsigned)nx < 64u; int cx = okx ? nx : (nx < 0 ? 0 : 63);
          float m = okx ? 1.0f : 0.0f;
          const float* src = h1 + ((size_t)((nz * 64 + ny) * 64 + cx)) * 64;
          const float* wr  = w2t + (size_t)((dz+1)*9 + (dy+1)*3 + (dx+1)) * 2048; // uniform

          float4 r[16];                       // whole 64-ch row in flight (one latency event)
          #pragma unroll
          for (int q = 0; q < 16; ++q) r[q] = reinterpret_cast<const float4*>(src)[q];

          #pragma unroll
          for (int q = 0; q < 16; ++q) {
            float vx = r[q].x * m, vy = r[q].y * m, vz = r[q].z * m, vw = r[q].w * m;
            const float* wc = wr + q * 4 * 32;
            #pragma unroll
            for (int o = 0; o < 32; ++o) acc[o] = fmaf(vx, wc[o],      acc[o]);
            #pragma unroll
            for (int o = 0; o < 32; ++o) acc[o] = fmaf(vy, wc[32 + o], acc[o]);
            #pragma unroll
            for (int o = 0; o < 32; ++o) acc[o] = fmaf(vz, wc[64 + o], acc[o]);
            #pragma unroll
            for (int o = 0; o < 32; ++o) acc[o] = fmaf(vw, wc[96 + o], acc[o]);
          }
        }
      }
    }

    float* dst = pf + ((size_t)((z * 64 + y) * 64 + x)) * 32;
    #pragma unroll
    for (int o = 0; o < 32; o += 4) {
        float4 v = make_float4(fmaxf(acc[o], 0.f), fmaxf(acc[o+1], 0.f),
                               fmaxf(acc[o+2], 0.f), fmaxf(acc[o+3], 0.f));
        *reinterpret_cast<float4*>(dst + o) = v;
    }
}

// ------- epilogue: heads + argmax + argmin over seeds + mismatch scatter -------
__global__ __launch_bounds__(256) void epilogue_kernel(
    const float* __restrict__ pf,     // [vox][32] post-relu
    const float* __restrict__ points, // [N][3]
    const float* __restrict__ ann,    // [512][4]
    const float* __restrict__ sem_w, const float* __restrict__ sem_b,
    const float* __restrict__ off_w, const float* __restrict__ off_b,
    float* __restrict__ out_logits,   // [N][20]
    float* __restrict__ out_off,      // [N][3]
    int* __restrict__ iv_out,         // [N]
    int* __restrict__ bad_seed)       // [512]
{
    __shared__ float4 sseed[NSEED];
    for (int i = threadIdx.x; i < NSEED; i += 256) {
        float4 a = *reinterpret_cast<const float4*>(ann + i * 4);
        sseed[i] = make_float4(a.x, a.y, a.z, a.x*a.x + a.y*a.y + a.z*a.z);
    }
    __syncthreads();

    int vox = blockIdx.x * 256 + threadIdx.x;

    float f[32];
    #pragma unroll
    for (int q = 0; q < 8; ++q) {
        float4 v = *reinterpret_cast<const float4*>(pf + (size_t)vox * 32 + q * 4);
        f[q*4+0] = v.x; f[q*4+1] = v.y; f[q*4+2] = v.z; f[q*4+3] = v.w;
    }

    // semantic head + argmax (strict > = first occurrence)
    float best = -1e30f; int am = 0;
    #pragma unroll
    for (int cc = 0; cc < NCLS; ++cc) {
        float l = sem_b[cc];
        #pragma unroll
        for (int q = 0; q < 32; ++q) l = fmaf(f[q], sem_w[cc * 32 + q], l);
        out_logits[(size_t)vox * NCLS + cc] = l;
        if (l > best) { best = l; am = cc; }
    }

    // offset head
    float off[3];
    #pragma unroll
    for (int k3 = 0; k3 < 3; ++k3) {
        float l = off_b[k3];
        #pragma unroll
        for (int q = 0; q < 32; ++q) l = fmaf(f[q], off_w[k3 * 32 + q], l);
        out_off[(size_t)vox * 3 + k3] = l;
        off[k3] = l;
    }

    float px = points[(size_t)vox * 3 + 0] + off[0];
    float py = points[(size_t)vox * 3 + 1] + off[1];
    float pz = points[(size_t)vox * 3 + 2] + off[2];
    float pp = px * px + py * py + pz * pz;

    float bd2 = 1e30f; int bj = 0;
    #pragma unroll 4
    for (int j = 0; j < NSEED; ++j) {
        float4 s = sseed[j];                    // broadcast, conflict-free
        float dot = px * s.x + py * s.y + pz * s.z;
        float d2  = pp + s.w - 2.0f * dot;
        if (d2 < bd2) { bd2 = d2; bj = j; }
    }
    float mind = sqrtf(fmaxf(bd2, 0.f));
    bool valid = mind < 1.5f;

    int slab = (int)ann[bj * 4 + 3];
    if (valid && am != slab) atomicOr(&bad_seed[bj], 1);
    iv_out[vox] = valid ? bj : -1;
}

// ---------------- finalize pseudo labels ----------------
__global__ void finalize_kernel(const int* __restrict__ iv,
                                const int* __restrict__ bad,
                                float* __restrict__ pl) {
    int t = blockIdx.x * 256 + threadIdx.x;
    if (t >= NVOX) return;
    int v = iv[t];
    float r = -1.0f;
    if (v >= 0 && bad[v] == 0) r = (float)v;
    pl[t] = r;
}

extern "C" void kernel_launch(void* const* d_in, const int* in_sizes, int n_in,
                              void* d_out, int out_size, void* d_ws, size_t ws_size,
                              hipStream_t stream) {
    const float* points   = (const float*)d_in[0];
    const float* features = (const float*)d_in[1];
    const float* ann      = (const float*)d_in[2];
    const float* w1       = (const float*)d_in[3];
    const float* b1       = (const float*)d_in[4];
    const float* w2       = (const float*)d_in[5];
    const float* b2       = (const float*)d_in[6];
    const float* sem_w    = (const float*)d_in[7];
    const float* sem_b    = (const float*)d_in[8];
    const float* off_w    = (const float*)d_in[9];
    const float* off_b    = (const float*)d_in[10];

    float* out        = (float*)d_out;
    float* out_logits = out;
    float* out_off    = out + (size_t)NVOX * NCLS;   // N*20
    float* out_pl     = out + (size_t)NVOX * 23;     // N*23

    // workspace layout (bytes, 256-aligned)
    char*  ws  = (char*)d_ws;
    float* w1t = (float*)(ws);                 //    41472 B
    float* w2t = (float*)(ws + 41472);         //   221184 B
    int*   bad = (int*)  (ws + 262656);        //     2048 B
    int*   iv  = (int*)  (ws + 264704);        //  1048576 B
    float* pf  = (float*)(ws + 1313280);       // 33554432 B
    float* h1  = (float*)(ws + 34867712);      // 67108864 B  (total ~97.3 MB)

    hipMemsetAsync(bad, 0, NSEED * sizeof(int), stream);
    transpose_all<<<257, 256, 0, stream>>>(w1, w1t, w2, w2t);
    conv1_kernel<<<1024, 256, 0, stream>>>(features, w1t, b1, h1);
    conv2_kernel<<<1024, 256, 0, stream>>>(h1, w2t, b2, pf);
    epilogue_kernel<<<1024, 256, 0, stream>>>(pf, points, ann,
        sem_w, sem_b, off_w, off_b, out_logits, out_off, iv, bad);
    finalize_kernel<<<1024, 256, 0, stream>>>(iv, bad, out_pl);
}